// Round 2
// baseline (121.899 us; speedup 1.0000x reference)
//
#include <hip/hip_runtime.h>
#include <math.h>

#define BB 8
#define SS 2048
#define DD 1024
#define MM 4096
#define dd 256
#define NCH 64          // S-chunks for x column-sum
#define CS (SS/NCH)     // 32 rows per chunk
#define KS 16           // k-splits for projections
#define KL (DD/KS)      // 64 k per split
#define RCH 16          // retrieval chunks
#define RCS (MM/RCH)    // 256 rows per chunk

// ---- ws layout (floats) ----
#define OFF_PART  0                                  // B*NCH*D = 524288
#define OFF_PP    (OFF_PART + BB*NCH*DD)             // 2*KS*B*d = 65536
#define OFF_PG    (OFF_PP + 2*KS*BB*dd)              // KS*B = 128
#define OFF_Q     (OFF_PG + KS*BB)                   // 2048
#define OFF_WV    (OFF_Q + BB*dd)                    // 2048
#define OFF_GATE  (OFF_WV + BB*dd)                   // 8
#define OFF_COMBO (OFF_GATE + BB)                    // 8
#define OFF_SC    (OFF_COMBO + BB)                   // 2*B*M = 65536
#define OFF_SUMS  (OFF_SC + 2*BB*MM)                 // 16
#define OFF_PRET  (OFF_SUMS + 2*BB)                  // B*RCH*d = 32768
#define OFF_ROUT  (OFF_PRET + BB*RCH*dd)             // B*D = 8192

// KA: partial column sums of x. grid = B*NCH, block=256, float4 per thread.
__global__ void ka_partial(const float* __restrict__ x, float* __restrict__ ws) {
    int blk = blockIdx.x;
    int chunk = blk % NCH;
    int b = blk / NCH;
    int t = threadIdx.x;
    const float4* x4 = (const float4*)(x + ((size_t)b*SS + (size_t)chunk*CS)*DD);
    float4 acc = make_float4(0.f,0.f,0.f,0.f);
    #pragma unroll 8
    for (int s = 0; s < CS; ++s) {
        float4 v = x4[s*(DD/4) + t];
        acc.x += v.x; acc.y += v.y; acc.z += v.z; acc.w += v.w;
    }
    ((float4*)(ws + OFF_PART))[((b*NCH + chunk) << 8) + t] = acc;
}

// KB: k-split projections. grid = 2*KS (which,ks), block=256.
//   phase1: xs[b][k] (mean) for this k-slice from partials
//   phase2: partial matvec vs Wq/Wv slice; which==0 wave0 also does Wg partial.
__global__ void kb_proj(const float* __restrict__ Wq, const float* __restrict__ Wv,
                        const float* __restrict__ Wg, float* __restrict__ ws) {
    __shared__ float xs[BB][KL];
    int blk = blockIdx.x;
    int ks = blk % KS;
    int which = blk / KS;
    int k0 = ks * KL;
    int t = threadIdx.x;
    // phase 1: 512 (b,k) entries, 2 per thread, each sums NCH chunks
    for (int e = t; e < BB*KL; e += 256) {
        int b = e >> 6;          // KL=64
        int k = e & (KL-1);
        const float* p = ws + OFF_PART + (size_t)(b*NCH)*DD + k0 + k;
        float acc = 0.f;
        #pragma unroll 8
        for (int c = 0; c < NCH; ++c) acc += p[(size_t)c*DD];
        xs[b][k] = acc * (1.0f/SS);
    }
    __syncthreads();
    // phase 2: partial matvec, output col t
    const float* W = (which == 0) ? Wq : Wv;
    float acc[BB];
    #pragma unroll
    for (int b = 0; b < BB; ++b) acc[b] = 0.f;
    for (int k = 0; k < KL; ++k) {
        float w = W[(size_t)(k0 + k)*dd + t];
        #pragma unroll
        for (int b = 0; b < BB; ++b) acc[b] += xs[b][k] * w;
    }
    #pragma unroll
    for (int b = 0; b < BB; ++b)
        ws[OFF_PP + (size_t)((which*KS + ks)*BB + b)*dd + t] = acc[b];
    // gate partials on wave 0 of which==0 blocks
    if (which == 0 && t < 64) {
        float wg = Wg[k0 + t];
        for (int b = 0; b < BB; ++b) {
            float v = xs[b][t] * wg;
            #pragma unroll
            for (int off = 32; off > 0; off >>= 1) v += __shfl_xor(v, off);
            if (t == 0) ws[OFF_PG + ks*BB + b] = v;
        }
    }
}

// KC: reduce projection partials. grid = 3, block = 256.
__global__ void kc_reduce(const float* __restrict__ bq, const float* __restrict__ bv,
                          const float* __restrict__ bg, float* __restrict__ ws) {
    int which = blockIdx.x;
    int t = threadIdx.x;
    if (which < 2) {
        for (int b = 0; b < BB; ++b) {
            float acc = 0.f;
            #pragma unroll
            for (int ks = 0; ks < KS; ++ks)
                acc += ws[OFF_PP + (size_t)((which*KS + ks)*BB + b)*dd + t];
            acc += (which == 0) ? bq[t] : bv[t];
            ws[(which == 0 ? OFF_Q : OFF_WV) + b*dd + t] = acc;
        }
    } else if (t < BB) {
        float g = 0.f;
        #pragma unroll
        for (int ks = 0; ks < KS; ++ks) g += ws[OFF_PG + ks*BB + t];
        ws[OFF_GATE + t] = 1.f / (1.f + __expf(-(g + bg[0])));
    }
}

// K3: scores -> exp, one wave per (which,b,m). grid = 2*B*M/4, block = 256.
__global__ void k3_scores(const float* __restrict__ memory, float* __restrict__ ws) {
    int wave = threadIdx.x >> 6;
    int lane = threadIdx.x & 63;
    int task = blockIdx.x*4 + wave;
    int m = task & (MM-1);
    int b = (task >> 12) & (BB-1);
    int which = task / (BB*MM);
    const float* row = (which == 0) ? (memory + (size_t)m*dd)
                                    : (memory + ((size_t)b*MM + m)*dd);
    const float4 a  = ((const float4*)row)[lane];
    const float4 qv = ((const float4*)(ws + OFF_Q + b*dd))[lane];
    float p = a.x*qv.x + a.y*qv.y + a.z*qv.z + a.w*qv.w;
    #pragma unroll
    for (int off = 32; off > 0; off >>= 1) p += __shfl_xor(p, off);
    if (lane == 0) ws[OFF_SC + (size_t)(which*BB + b)*MM + m] = __expf(p);
}

// K45: role-split. blocks 0..15: row sums of exp-scores. blocks 16..143: partial retrieved.
__global__ void k45_sum_ret(const float* __restrict__ memory, float* __restrict__ ws) {
    __shared__ float red[256];
    int blk = blockIdx.x;
    int t = threadIdx.x;
    if (blk < 16) {
        const float* p = ws + OFF_SC + (size_t)blk*MM;
        float s = 0.f;
        #pragma unroll 4
        for (int i = t; i < MM; i += 256) s += p[i];
        red[t] = s; __syncthreads();
        for (int s2 = 128; s2 > 0; s2 >>= 1) {
            if (t < s2) red[t] += red[t + s2];
            __syncthreads();
        }
        if (t == 0) ws[OFF_SUMS + blk] = red[0];
    } else {
        int idx = blk - 16;
        int chunk = idx & (RCH-1);
        int b = idx >> 4;
        red[t] = ws[OFF_SC + (size_t)b*MM + chunk*RCS + t];   // exp read-scores chunk
        __syncthreads();
        float acc = 0.f;
        const float* pat = memory + (size_t)chunk*RCS*dd + t;
        #pragma unroll 4
        for (int m2 = 0; m2 < RCS; ++m2) acc += red[m2] * pat[(size_t)m2*dd];
        ws[OFF_PRET + (size_t)(b*RCH + chunk)*dd + t] = acc;
    }
}

// K6: retrieved reduce + normalize + Wo matvec. grid=(B,4), block=256.
__global__ void k6_rout(const float* __restrict__ Wo, const float* __restrict__ bo,
                        float* __restrict__ ws) {
    __shared__ float ret[dd];
    int b = blockIdx.x, cb = blockIdx.y, t = threadIdx.x;
    float acc = 0.f;
    #pragma unroll
    for (int c = 0; c < RCH; ++c) acc += ws[OFF_PRET + (size_t)(b*RCH + c)*dd + t];
    ret[t] = acc / ws[OFF_SUMS + b];
    if (cb == 0 && t == 0)
        ws[OFF_COMBO + b] = 0.05f * ws[OFF_GATE + b] / ws[OFF_SUMS + BB + b];
    __syncthreads();
    int col = cb*256 + t;
    float o = bo[col];
    #pragma unroll 4
    for (int j = 0; j < dd; ++j) o += ret[j] * Wo[(size_t)j*DD + col];
    ws[OFF_ROUT + (size_t)b*DD + col] = o;
}

// KE: fused elementwise: x_aug and memory_new. float4 grid-stride.
__global__ void ke_elem(const float* __restrict__ x, const float* __restrict__ memory,
                        const float* __restrict__ ws, float* __restrict__ out) {
    const int NA = BB*SS*DD/4;       // 4194304
    const int NT = NA + BB*MM*dd/4;  // 6291456
    const float4* x4 = (const float4*)x;
    const float4* m4 = (const float4*)memory;
    const float4* r4 = (const float4*)(ws + OFF_ROUT);
    const float4* w4 = (const float4*)(ws + OFF_WV);
    float4* o4 = (float4*)out;
    int stride = gridDim.x * blockDim.x;
    for (int i = blockIdx.x*blockDim.x + threadIdx.x; i < NT; i += stride) {
        if (i < NA) {
            int b = i >> 19;              // SS*DD/4 = 524288
            int c = i & 255;              // DD/4-1
            float4 xv = x4[i];
            float4 rv = r4[(b << 8) + c];
            o4[i] = make_float4(xv.x+rv.x, xv.y+rv.y, xv.z+rv.z, xv.w+rv.w);
        } else {
            int j = i - NA;
            int b = j >> 18;              // MM*dd/4 = 262144
            int m = (j >> 6) & (MM-1);
            int d4 = j & 63;
            float coeff = ws[OFF_COMBO + b] * ws[OFF_SC + (size_t)(BB + b)*MM + m];
            float4 wv = w4[(b << 6) + d4];
            float4 mv = m4[j];
            o4[i] = make_float4(0.95f*mv.x + coeff*wv.x,
                                0.95f*mv.y + coeff*wv.y,
                                0.95f*mv.z + coeff*wv.z,
                                0.95f*mv.w + coeff*wv.w);
        }
    }
}

extern "C" void kernel_launch(void* const* d_in, const int* in_sizes, int n_in,
                              void* d_out, int out_size, void* d_ws, size_t ws_size,
                              hipStream_t stream) {
    const float* x      = (const float*)d_in[0];
    const float* memory = (const float*)d_in[1];
    const float* Wq     = (const float*)d_in[2];
    const float* bq     = (const float*)d_in[3];
    const float* Wv     = (const float*)d_in[4];
    const float* bv     = (const float*)d_in[5];
    const float* Wo     = (const float*)d_in[6];
    const float* bo     = (const float*)d_in[7];
    const float* Wg     = (const float*)d_in[8];
    const float* bg     = (const float*)d_in[9];
    float* out = (float*)d_out;
    float* ws  = (float*)d_ws;

    ka_partial<<<BB*NCH, 256, 0, stream>>>(x, ws);
    kb_proj<<<2*KS, 256, 0, stream>>>(Wq, Wv, Wg, ws);
    kc_reduce<<<3, 256, 0, stream>>>(bq, bv, bg, ws);
    k3_scores<<<2*BB*MM/4, 256, 0, stream>>>(memory, ws);
    k45_sum_ret<<<16 + BB*RCH, 256, 0, stream>>>(memory, ws);
    k6_rout<<<dim3(BB,4), 256, 0, stream>>>(Wo, bo, ws);
    ke_elem<<<4096, 256, 0, stream>>>(x, memory, ws, out);
}

// Round 3
// 78.362 us; speedup vs baseline: 1.5556x; 1.5556x over previous
//
#include <hip/hip_runtime.h>
#include <math.h>

#define BB 8
#define SS 2048
#define DD 1024
#define MM 4096
#define dd 256
#define NCH 64          // S-chunks for x column-sum
#define CS (SS/NCH)     // 32 rows per chunk
#define KSL 32          // k-slices for projections (32 k each)

// ---- ws layout (floats) ----
#define OFF_PART  0                        // float4[(b*64+chunk)*256+t] = 524288 floats
#define OFF_PP    524288                   // [which*32+ks][b*256+col] = 131072
#define OFF_PG    655360                   // [b*32+ks] = 256
#define OFF_Q     655616                   // 2048
#define OFF_WV    657664                   // 2048
#define OFF_GATE  659712                   // 8
#define OFF_COMBO 659720                   // 8
#define OFF_SUMS  659728                   // 16
#define OFF_SC    659744                   // [which*8+b][m] = 65536
#define OFF_PRET  725280                   // [(b*64+mc)*256+j] = 131072
#define OFF_RET   856352                   // 2048
#define OFF_ROUT  858400                   // 8192

// K1: x partial column sums. grid = B*NCH = 512, block 256, float4/thread.
__global__ void k1(const float* __restrict__ x, float* __restrict__ ws) {
    int blk = blockIdx.x;
    int chunk = blk & 63;
    int b = blk >> 6;
    int t = threadIdx.x;
    const float4* x4 = (const float4*)(x + ((size_t)b*SS + (size_t)chunk*CS)*DD);
    float4 a = make_float4(0.f,0.f,0.f,0.f);
    #pragma unroll 8
    for (int s = 0; s < CS; ++s) {
        float4 v = x4[s*(DD/4) + t];
        a.x += v.x; a.y += v.y; a.z += v.z; a.w += v.w;
    }
    ((float4*)(ws + OFF_PART))[(size_t)(b*NCH + chunk)*256 + t] = a;
}

// K2: per-block xs k-slice + projection slice. grid = 2*KSL = 64, block 256.
__global__ void k2(const float* __restrict__ Wq, const float* __restrict__ Wv,
                   const float* __restrict__ Wg, float* __restrict__ ws) {
    __shared__ float xs[BB][KSL];
    int blk = blockIdx.x;
    int ks = blk & 31;
    int which = blk >> 5;
    int t = threadIdx.x;
    // build xs[b][32 k's] from float4 partials: entry e=(b,kk) handled by 4 lanes
    int e = t >> 2;            // 0..63
    int b = e >> 3;            // 0..7
    int kk = e & 7;            // float4 index within slice
    int k4 = ks*8 + kk;        // global float4 column
    int q = t & 3;
    const float4* p4 = (const float4*)(ws + OFF_PART);
    float4 a = make_float4(0.f,0.f,0.f,0.f);
    #pragma unroll
    for (int i = 0; i < 16; ++i) {
        float4 v = p4[(size_t)(b*NCH + q*16 + i)*256 + k4];
        a.x += v.x; a.y += v.y; a.z += v.z; a.w += v.w;
    }
    #pragma unroll
    for (int off = 1; off < 4; off <<= 1) {
        a.x += __shfl_xor(a.x, off); a.y += __shfl_xor(a.y, off);
        a.z += __shfl_xor(a.z, off); a.w += __shfl_xor(a.w, off);
    }
    if (q == 0) {
        xs[b][kk*4+0] = a.x * (1.0f/SS); xs[b][kk*4+1] = a.y * (1.0f/SS);
        xs[b][kk*4+2] = a.z * (1.0f/SS); xs[b][kk*4+3] = a.w * (1.0f/SS);
    }
    __syncthreads();
    const float* W = which ? Wv : Wq;
    float acc[BB];
    #pragma unroll
    for (int b2 = 0; b2 < BB; ++b2) acc[b2] = 0.f;
    #pragma unroll 4
    for (int kk2 = 0; kk2 < KSL; ++kk2) {
        float w = W[(size_t)(ks*KSL + kk2)*dd + t];
        #pragma unroll
        for (int b2 = 0; b2 < BB; ++b2) acc[b2] += xs[b2][kk2] * w;
    }
    #pragma unroll
    for (int b2 = 0; b2 < BB; ++b2)
        ws[OFF_PP + (size_t)(which*KSL + ks)*2048 + b2*dd + t] = acc[b2];
    if (which == 0) {
        int gb = t >> 5, gk = t & 31;
        float v = xs[gb][gk] * Wg[ks*KSL + gk];
        #pragma unroll
        for (int off = 16; off > 0; off >>= 1) v += __shfl_xor(v, off);
        if (gk == 0) ws[OFF_PG + gb*32 + ks] = v;
    }
}

// K3: reduce projection partials + bias; gate sigmoid. grid = 17, block 256.
__global__ void k3(const float* __restrict__ bq, const float* __restrict__ bv,
                   const float* __restrict__ bg, float* __restrict__ ws) {
    int blk = blockIdx.x;
    int t = threadIdx.x;
    if (blk < 16) {
        int which = blk >> 3, b = blk & 7;
        float acc = 0.f;
        #pragma unroll
        for (int ks = 0; ks < KSL; ++ks)
            acc += ws[OFF_PP + (size_t)(which*KSL + ks)*2048 + b*dd + t];
        acc += which ? bv[t] : bq[t];
        ws[(which ? OFF_WV : OFF_Q) + b*dd + t] = acc;
    } else if (t < BB) {
        float g = 0.f;
        #pragma unroll
        for (int i = 0; i < 32; ++i) g += ws[OFF_PG + t*32 + i];
        ws[OFF_GATE + t] = 1.f / (1.f + __expf(-(g + bg[0])));
    }
}

// K4: scores -> exp. one wave per (which,b,m). grid = 2*B*M/4 = 16384, block 256.
__global__ void k4(const float* __restrict__ memory, float* __restrict__ ws) {
    int wave = threadIdx.x >> 6;
    int lane = threadIdx.x & 63;
    int task = blockIdx.x*4 + wave;
    int m = task & (MM-1);
    int b = (task >> 12) & 7;
    int which = task >> 15;
    const float* row = (which == 0) ? (memory + (size_t)m*dd)
                                    : (memory + ((size_t)b*MM + m)*dd);
    const float4 a  = ((const float4*)row)[lane];
    const float4 qv = ((const float4*)(ws + OFF_Q + b*dd))[lane];
    float p = a.x*qv.x + a.y*qv.y + a.z*qv.z + a.w*qv.w;
    #pragma unroll
    for (int off = 32; off > 0; off >>= 1) p += __shfl_xor(p, off);
    if (lane == 0) ws[OFF_SC + (size_t)(which*BB + b)*MM + m] = __expf(p);
}

// K5: blocks 0..15 row sums; blocks 16..527 retrieval partials (m-chunks of 64).
__global__ void k5(const float* __restrict__ memory, float* __restrict__ ws) {
    __shared__ float red[256];
    int blk = blockIdx.x;
    int t = threadIdx.x;
    if (blk < 16) {
        const float4* p = (const float4*)(ws + OFF_SC + (size_t)blk*MM);
        float s = 0.f;
        #pragma unroll
        for (int i = 0; i < 4; ++i) {
            float4 v = p[i*256 + t];
            s += v.x + v.y + v.z + v.w;
        }
        red[t] = s; __syncthreads();
        for (int s2 = 128; s2 > 0; s2 >>= 1) {
            if (t < s2) red[t] += red[t + s2];
            __syncthreads();
        }
        if (t == 0) ws[OFF_SUMS + blk] = red[0];
    } else {
        int idx = blk - 16;
        int mc = idx & 63;
        int b = idx >> 6;
        if (t < 64) red[t] = ws[OFF_SC + (size_t)b*MM + mc*64 + t];
        __syncthreads();
        float acc = 0.f;
        const float* pat = memory + (size_t)mc*64*dd + t;
        #pragma unroll 8
        for (int i = 0; i < 64; ++i) acc += red[i] * pat[(size_t)i*dd];
        ws[OFF_PRET + (size_t)(b*64 + mc)*dd + t] = acc;
    }
}

// K6: finish retrieved (normalize) + combo scalar. grid = 8, block 256.
__global__ void k6(float* __restrict__ ws) {
    int b = blockIdx.x;
    int t = threadIdx.x;
    float acc = 0.f;
    #pragma unroll 8
    for (int mc = 0; mc < 64; ++mc)
        acc += ws[OFF_PRET + (size_t)(b*64 + mc)*dd + t];
    ws[OFF_RET + b*dd + t] = acc / ws[OFF_SUMS + b];
    if (t == 0)
        ws[OFF_COMBO + b] = 0.05f * ws[OFF_GATE + b] / ws[OFF_SUMS + BB + b];
}

// K7: rout = ret @ Wo + bo. grid = B*16 = 128, block 256 (4-way j-split).
__global__ void k7(const float* __restrict__ Wo, const float* __restrict__ bo,
                   float* __restrict__ ws) {
    __shared__ float ret[dd];
    __shared__ float red[256];
    int blk = blockIdx.x;
    int cb = blk & 15;
    int b = blk >> 4;
    int t = threadIdx.x;
    ret[t] = ws[OFF_RET + b*dd + t];
    __syncthreads();
    int c = t & 63, jr = t >> 6;
    float acc = 0.f;
    #pragma unroll 8
    for (int jj = 0; jj < 64; ++jj) {
        int j = jr*64 + jj;
        acc += ret[j] * Wo[(size_t)j*DD + cb*64 + c];
    }
    red[t] = acc; __syncthreads();
    if (t < 64) {
        float o = red[t] + red[t+64] + red[t+128] + red[t+192] + bo[cb*64 + t];
        ws[OFF_ROUT + (size_t)b*DD + cb*64 + t] = o;
    }
}

// K8: fused elementwise outputs. float4 grid-stride, grid 4096.
__global__ void k8(const float* __restrict__ x, const float* __restrict__ memory,
                   const float* __restrict__ ws, float* __restrict__ out) {
    const int NA = BB*SS*DD/4;       // 4194304
    const int NT = NA + BB*MM*dd/4;  // 6291456
    const float4* x4 = (const float4*)x;
    const float4* m4 = (const float4*)memory;
    const float4* r4 = (const float4*)(ws + OFF_ROUT);
    const float4* w4 = (const float4*)(ws + OFF_WV);
    float4* o4 = (float4*)out;
    int stride = gridDim.x * blockDim.x;
    for (int i = blockIdx.x*blockDim.x + threadIdx.x; i < NT; i += stride) {
        if (i < NA) {
            int b = i >> 19;
            int c = i & 255;
            float4 xv = x4[i];
            float4 rv = r4[(b << 8) + c];
            o4[i] = make_float4(xv.x+rv.x, xv.y+rv.y, xv.z+rv.z, xv.w+rv.w);
        } else {
            int j = i - NA;
            int b = j >> 18;
            int m = (j >> 6) & (MM-1);
            int d4 = j & 63;
            float coeff = ws[OFF_COMBO + b] * ws[OFF_SC + (size_t)(BB + b)*MM + m];
            float4 wv = w4[(b << 6) + d4];
            float4 mv = m4[j];
            o4[i] = make_float4(0.95f*mv.x + coeff*wv.x,
                                0.95f*mv.y + coeff*wv.y,
                                0.95f*mv.z + coeff*wv.z,
                                0.95f*mv.w + coeff*wv.w);
        }
    }
}

extern "C" void kernel_launch(void* const* d_in, const int* in_sizes, int n_in,
                              void* d_out, int out_size, void* d_ws, size_t ws_size,
                              hipStream_t stream) {
    const float* x      = (const float*)d_in[0];
    const float* memory = (const float*)d_in[1];
    const float* Wq     = (const float*)d_in[2];
    const float* bq     = (const float*)d_in[3];
    const float* Wv     = (const float*)d_in[4];
    const float* bv     = (const float*)d_in[5];
    const float* Wo     = (const float*)d_in[6];
    const float* bo     = (const float*)d_in[7];
    const float* Wg     = (const float*)d_in[8];
    const float* bg     = (const float*)d_in[9];
    float* out = (float*)d_out;
    float* ws  = (float*)d_ws;

    k1<<<BB*NCH, 256, 0, stream>>>(x, ws);
    k2<<<2*KSL, 256, 0, stream>>>(Wq, Wv, Wg, ws);
    k3<<<17, 256, 0, stream>>>(bq, bv, bg, ws);
    k4<<<2*BB*MM/4, 256, 0, stream>>>(memory, ws);
    k5<<<16 + BB*64, 256, 0, stream>>>(memory, ws);
    k6<<<BB, 256, 0, stream>>>(ws);
    k7<<<BB*16, 256, 0, stream>>>(Wo, bo, ws);
    k8<<<4096, 256, 0, stream>>>(x, memory, ws, out);
}